// Round 12
// baseline (168.182 us; speedup 1.0000x reference)
//
#include <hip/hip_runtime.h>
#include <math.h>

#define NLEV 5
#define TOPKK 1000
#define NCLS 16
#define NPART 16                 // cand partitions (by chunk id)
#define HP 16u                   // histogram partial copies
#define PART_CAP 256
#define CAND_TOT 2048
#define NCHUNK 3069u             // 785664 / 256
#define HISTSZ (NLEV * 256)      // 1280 u32 per copy
#define HIST_U32 (HP * HISTSZ)   // 20480 u32 per hist per bank
#define CNT_U32 (NLEV * NPART * 16)          // 1280 u32 (padded counters)
#define BAR_U32 5120u            // per instance: flags[0..1023], go @1024+b*4
#define CLEAN_U32 (2u * HIST_U32 + CNT_U32)  // next-bank words to zero

// ---- persistent device state (module .bss: zero at load, NOT poisoned) ---
// Epoch-tagged barriers + bank-alternating hist/cnt: no per-launch memset.
// Launch e tags barrier words with e+1 (stale tags never alias), uses
// hist/cnt bank e&1, zeroes bank (e+1)&1 for the next launch. g_epoch is
// device state -> correct under graph-capture and rocprof replays.
__device__ unsigned g_epoch;
__device__ unsigned g_bar[3u * BAR_U32];
__device__ unsigned g_hist[2][2][HIST_U32];    // [bank][A=0/B=1][...]
__device__ unsigned g_cnt[2][CNT_U32];
__device__ unsigned long long g_cand[NLEV * NPART * PART_CAP];

// LLC-coherent accessors: agent-scope relaxed atomics bypass per-XCD L2 and
// serialize at the LLC. All cross-block data uses these; no release/acquire
// fences anywhere (gfx950 fences lower to buffer_wbl2/buffer_inv = full-L2
// writeback/invalidate -- ~7us/barrier, removed in r7).
__device__ __forceinline__ unsigned g_load(const unsigned* p) {
    return __hip_atomic_load(p, __ATOMIC_RELAXED, __HIP_MEMORY_SCOPE_AGENT);
}
__device__ __forceinline__ unsigned long long g_load64(const unsigned long long* p) {
    return __hip_atomic_load(p, __ATOMIC_RELAXED, __HIP_MEMORY_SCOPE_AGENT);
}
__device__ __forceinline__ void g_store(unsigned* p, unsigned v) {
    __hip_atomic_store(p, v, __ATOMIC_RELAXED, __HIP_MEMORY_SCOPE_AGENT);
}
__device__ __forceinline__ void g_store64(unsigned long long* p, unsigned long long v) {
    __hip_atomic_store(p, v, __ATOMIC_RELAXED, __HIP_MEMORY_SCOPE_AGENT);
}

// chunk-index level boundaries: 2304, 2880, 3024, 3060 — divisible by 3 and
// 6, so blocks are level-pure for CPB in {3,6}.
__device__ __forceinline__ int lev_of_chunk(unsigned c) {
    if (c < 2304u) return 0;
    if (c < 2880u) return 1;
    if (c < 3024u) return 2;
    if (c < 3060u) return 3;
    return 4;
}
__device__ __forceinline__ unsigned lev_base(int l) {   // entry base per level
    unsigned b = 0u;
    if (l == 1) b = 589824u;
    if (l == 2) b = 737280u;
    if (l == 3) b = 774144u;
    if (l == 4) b = 783360u;
    return b;
}

struct Ptrs {
    const float* anc[NLEV];
    const float* cls[NLEV];
    const float* reg[NLEV];
};

// order-preserving float32 -> uint32 (larger uint == larger float)
__device__ __forceinline__ unsigned f2key(float f) {
    unsigned u = __float_as_uint(f);
    return (u & 0x80000000u) ? ~u : (u | 0x80000000u);
}

__device__ __forceinline__ float max4(float4 v) {
    return fmaxf(fmaxf(v.x, v.y), fmaxf(v.z, v.w));
}

// ---- fence-free store-based grid barrier (r7-r11 design, epoch-tagged) ---
//   flags[b]   = inst[b]             one word per block, tagged with e+1
//   go[b]      = inst[1024 + b*4]    PRIVATE go word per block (16B stride)
// ORDERING: __syncthreads() before arrival drains vmcnt(0) in every wave, so
// all the block's LLC-bound atomics complete before the flag store; all
// cross-block data moves via agent-scope atomics (LLC = serialization
// point) => flag-observed implies data-visible. No wbl2/inv anywhere.
__device__ __forceinline__ void bar_arrive(unsigned* inst, unsigned tag) {
    if (threadIdx.x == 0) g_store(inst + blockIdx.x, tag);
}

// block 0 only, ALL threads participate. Sweep uses INDEPENDENT loads.
template<unsigned NBV>
__device__ __forceinline__ void bar_monitor_fanout(unsigned* inst, unsigned* wsh,
                                                   unsigned tag) {
    const int t = threadIdx.x;
    for (;;) {
        unsigned f0 = g_load(inst + t);
        unsigned f1 = (256u + (unsigned)t < NBV) ? g_load(inst + 256 + t) : tag;
        unsigned f2 = (NBV > 512u && 512u + (unsigned)t < NBV) ? g_load(inst + 512 + t) : tag;
        unsigned f3 = (NBV > 768u && 768u + (unsigned)t < NBV) ? g_load(inst + 768 + t) : tag;
        bool all = (f0 == tag) && (f1 == tag) && (f2 == tag) && (f3 == tag);
        unsigned long long bal = __ballot(all);
        if ((t & 63) == 0) wsh[t >> 6] = (bal == 0xFFFFFFFFFFFFFFFFull) ? 1u : 0u;
        __syncthreads();
        bool done = wsh[0] && wsh[1] && wsh[2] && wsh[3];
        __syncthreads();
        if (done) break;
        __builtin_amdgcn_s_sleep(1);
    }
    for (unsigned idx = (unsigned)t; idx < NBV; idx += 256u)   // private go words
        g_store(inst + 1024u + idx * 4u, tag);
}

__device__ __forceinline__ void bar_waitgo(unsigned* inst, unsigned tag) {
    while (g_load(inst + 1024u + blockIdx.x * 4u) != tag)
        __builtin_amdgcn_s_sleep(2);
}

template<unsigned NBV>
__device__ __forceinline__ void gridbar(unsigned* inst, unsigned* wsh, unsigned tag) {
    __syncthreads();                       // drains vmcnt in all waves
    bar_arrive(inst, tag);
    if (blockIdx.x == 0) {
        bar_monitor_fanout<NBV>(inst, wsh, tag);
    } else if (threadIdx.x == 0) {
        bar_waitgo(inst, tag);
    }
    __syncthreads();
}

// suffix-select over 256 bins (bin == threadIdx) via wave shuffles.
// Finds bin holding the rem-th largest; aux[0]=bin, aux[1]=remainder.
// (verbatim r5-r11 core, absmax-0 verified)
__device__ __forceinline__ void sel256(unsigned c, unsigned rem,
                                       unsigned* wsum, unsigned* aux) {
    int t = threadIdx.x, lane = t & 63, wv = t >> 6;
    unsigned s = c;                          // suffix-sum over lanes >= mine
    #pragma unroll
    for (int d = 1; d < 64; d <<= 1) {
        unsigned o = __shfl_down(s, d, 64);
        if (lane + d < 64) s += o;
    }
    if (lane == 0) wsum[wv] = s;             // wave total
    __syncthreads();
    unsigned incl = s;                       // + totals of higher-bin waves
    #pragma unroll
    for (int w2 = 1; w2 < 4; w2++) if (wv + w2 < 4) incl += wsum[wv + w2];
    unsigned above = incl - c;
    if (above < rem && rem <= incl) {        // exactly one winner thread
        aux[0] = (unsigned)t;
        aux[1] = rem - above;
    }
    __syncthreads();
}

// ILP copy-sum: issue all HP hist-copy loads before summing (one vmcnt wait
// instead of a 16-deep serialized LLC chain -- the r9 lesson).
__device__ __forceinline__ unsigned hist_sum(const unsigned* hist, int lev) {
    unsigned vv[HP];
    #pragma unroll
    for (unsigned pp = 0; pp < HP; pp++)
        vv[pp] = g_load(hist + pp * HISTSZ + (unsigned)lev * 256u
                        + (unsigned)threadIdx.x);
    unsigned s = 0;
    #pragma unroll
    for (unsigned pp = 0; pp < HP; pp++) s += vv[pp];
    return s;
}

// One persistent kernel, ONE dispatch: level-pure blocks, keys in registers,
// fence-free epoch-tagged barriers, LLC-scope cross-block data, coalesced
// FULLY-HOISTED phase-A loads (12 outstanding/thread -> BW-bound, the r11
// lesson: 4-deep MLP left phase A at half the HBM ceiling). Cleanup moved
// AFTER bar2 arrival (off the critical path). Selection bit-identical r0.
template<unsigned CPBV, unsigned NBV>
__global__ __launch_bounds__(256, 2) void k_fused(Ptrs p, float* out) {
    __shared__ unsigned long long lbuf[CAND_TOT];   // 16 KB (rank phase only)
    __shared__ unsigned hh[256];
    __shared__ unsigned wsum[4];
    __shared__ unsigned wsh[4];
    __shared__ unsigned aux[33];

    const unsigned b = blockIdx.x;
    const int t = threadIdx.x;
    const unsigned c0 = b * CPBV;
    const int lev = lev_of_chunk(c0);
    const unsigned ebase = lev_base(lev);

    const unsigned e   = g_load(&g_epoch);   // stable: prev launch fully done
    const unsigned tag = e + 1u;             // never aliases stale (.bss=0)
    const unsigned bk  = e & 1u;
    unsigned* histA = g_hist[bk][0];
    unsigned* histB = g_hist[bk][1];
    unsigned* cnt   = g_cnt[bk];
    unsigned* bar0 = g_bar;
    unsigned* bar1 = g_bar + BAR_U32;
    unsigned* bar2 = g_bar + 2u * BAR_U32;

    // ---- Phase A1: ALL loads hoisted (CPBV*4 outstanding float4s/thread),
    // then 4-lane shuffle max-reduce. Thread t loads float4 #(g*256+t) of
    // each chunk (16B lane stride, fully coalesced); thread t keeps entry
    // eloc = (t&3)*64 + (t>>2) (bijection; hist is permutation-invariant,
    // compact stores loc explicitly -> output bit-identical).
    unsigned keys[CPBV];
    const float4* f4p = (const float4*)(p.cls[lev]);
    float4 aa[CPBV][4];
    #pragma unroll
    for (unsigned j = 0; j < CPBV; j++) {
        unsigned ch = c0 + j;
        if (CPBV == 3u || ch < NCHUNK) {       // 1023*3 == 3069 exact
            unsigned base4 = (ch * 256u - ebase) * 4u;
            #pragma unroll
            for (unsigned g = 0; g < 4u; g++)
                aa[j][g] = f4p[base4 + g * 256u + (unsigned)t];
        }
    }
    #pragma unroll
    for (unsigned j = 0; j < CPBV; j++) {
        unsigned k = 0u;
        if (CPBV == 3u || (c0 + j) < NCHUNK) {
            float m0 = max4(aa[j][0]), m1 = max4(aa[j][1]);
            float m2 = max4(aa[j][2]), m3 = max4(aa[j][3]);
            m0 = fmaxf(m0, __shfl_xor(m0, 1, 64));
            m0 = fmaxf(m0, __shfl_xor(m0, 2, 64));
            m1 = fmaxf(m1, __shfl_xor(m1, 1, 64));
            m1 = fmaxf(m1, __shfl_xor(m1, 2, 64));
            m2 = fmaxf(m2, __shfl_xor(m2, 1, 64));
            m2 = fmaxf(m2, __shfl_xor(m2, 2, 64));
            m3 = fmaxf(m3, __shfl_xor(m3, 1, 64));
            m3 = fmaxf(m3, __shfl_xor(m3, 2, 64));
            int g = t & 3;
            float mm = (g == 0) ? m0 : (g == 1) ? m1 : (g == 2) ? m2 : m3;
            k = f2key(mm);
        }
        keys[j] = k;
    }
    // ---- Phase A2: block byte-1 hist; one flush into 1-of-16 copies ----
    hh[t] = 0u;
    __syncthreads();
    #pragma unroll
    for (unsigned j = 0; j < CPBV; j++)
        if (CPBV == 3u || c0 + j < NCHUNK) atomicAdd(&hh[keys[j] >> 24], 1u);
    __syncthreads();
    {
        unsigned v = hh[t];
        if (v) atomicAdd(&histA[(b & (HP - 1u)) * HISTSZ
                                + (unsigned)lev * 256u + (unsigned)t], v);
    }
    gridbar<NBV>(bar0, wsh, tag);

    // ---- Select byte-1 for OWN level only (ILP copy-sum) ----
    sel256(hist_sum(histA, lev), TOPKK, wsum, aux);
    unsigned binA = aux[0], remA = aux[1];
    __syncthreads();

    // ---- Phase C: byte-2 hist of keys matching byte-1 prefix ----
    hh[t] = 0u;
    __syncthreads();
    #pragma unroll
    for (unsigned j = 0; j < CPBV; j++) {
        unsigned k = keys[j];
        if ((CPBV == 3u || (c0 + j) < NCHUNK) && (k >> 24) == binA)
            atomicAdd(&hh[(k >> 16) & 0xFFu], 1u);
    }
    __syncthreads();
    {
        unsigned v = hh[t];
        if (v) atomicAdd(&histB[(b & (HP - 1u)) * HISTSZ
                                + (unsigned)lev * 256u + (unsigned)t], v);
    }
    gridbar<NBV>(bar1, wsh, tag);

    // ---- Select byte-2 -> 16-bit threshold (identical semantics) ----
    sel256(hist_sum(histB, lev), remA, wsum, aux);
    unsigned thresh = (binA << 24) | (aux[0] << 16);
    __syncthreads();

    // ---- Phase E: compact candidates (loc uses the phase-A permutation) ----
    const unsigned eloc = (((unsigned)t & 3u) << 6) | ((unsigned)t >> 2);
    #pragma unroll
    for (unsigned j = 0; j < CPBV; j++) {
        unsigned ch = c0 + j;
        unsigned k = keys[j];
        if ((CPBV == 3u || ch < NCHUNK) && k >= thresh) {
            unsigned loc = ch * 256u - ebase + eloc;
            unsigned part = ch & (NPART - 1u);
            unsigned slot = atomicAdd(&cnt[(lev * NPART + part) * 16u], 1u);
            if (slot < PART_CAP)
                g_store64(&g_cand[((size_t)(lev * NPART + part)) * PART_CAP + slot],
                          ((unsigned long long)k << 32) | (unsigned)(~loc));
        }
    }

    // ---- Exit-flag: everyone arrives FIRST; cleanup runs AFTER arrival
    //      (off the barrier critical path; touches only bank bk^1, disjoint
    //      from everything phase F reads) ----
    bool ranker = b < (unsigned)(NLEV * 8);
    __syncthreads();                       // drains vmcnt (cand stores acked)
    bar_arrive(bar2, tag);
    {
        unsigned bk1 = bk ^ 1u;
        for (unsigned i = b * 256u + (unsigned)t; i < CLEAN_U32; i += NBV * 256u) {
            if (i < 2u * HIST_U32) g_store(&g_hist[bk1][0][0] + i, 0u);
            else                   g_store(&g_cnt[bk1][i - 2u * HIST_U32], 0u);
        }
    }
    if (b == 0) {
        bar_monitor_fanout<NBV>(bar2, wsh, tag);
        if (t == 0) g_store(&g_epoch, tag);   // all blocks arrived: safe
    } else if (ranker) {
        if (t == 0) bar_waitgo(bar2, tag);
    } else {
        return;                               // cleanup stores retire before kernel end
    }
    __syncthreads();

    // ---- Phase F: rank-by-counting + emit (verified round-0 logic) ----
    const float MAXD = 4.135166556742356f;   // log(1000/16)
    int l = (int)(b >> 3);
    unsigned sl = b & 7u;

    if (t < NPART) {
        unsigned cc = g_load(cnt + (l * NPART + t) * 16u);
        aux[t] = (cc > PART_CAP) ? PART_CAP : cc;
    }
    __syncthreads();
    if (t == 0) {
        unsigned o = 0;
        for (int pp = 0; pp < NPART; pp++) { aux[16 + pp] = o; o += aux[pp]; }
        aux[32] = (o > CAND_TOT) ? CAND_TOT : o;
    }
    __syncthreads();
    unsigned n = aux[32];
    {
        // each thread handles entry #t of each part: 16 guarded INDEPENDENT
        // loads, then 16 LDS stores (ILP-batched).
        unsigned long long tv[NPART];
        unsigned vok = 0u;
        #pragma unroll
        for (int pp = 0; pp < NPART; pp++) {
            bool ok = (unsigned)t < aux[pp];
            if (ok) tv[pp] = g_load64(&g_cand[((size_t)(l * NPART + pp)) * PART_CAP
                                              + (unsigned)t]);
            vok |= ok ? (1u << pp) : 0u;
        }
        #pragma unroll
        for (int pp = 0; pp < NPART; pp++) {
            if (vok & (1u << pp)) {
                unsigned dst = aux[16 + pp] + (unsigned)t;
                if (dst < CAND_TOT) lbuf[dst] = tv[pp];
            }
        }
    }
    __syncthreads();

    unsigned j = sl * 256u + (unsigned)t;
    if (j >= n) return;
    unsigned long long my = lbuf[j];
    unsigned rank = 0;
    #pragma unroll 8
    for (unsigned q = 0; q < n; q++) rank += (lbuf[q] > my) ? 1u : 0u;
    if (rank >= TOPKK) return;

    unsigned idx = ~((unsigned)(my & 0xFFFFFFFFull));
    float4 an = ((const float4*)p.anc[l])[idx];
    float4 dd = ((const float4*)p.reg[l])[(size_t)idx * 2];
    float w = an.z - an.x, h = an.w - an.y;
    float cx = an.x + 0.5f * w, cy = an.y + 0.5f * h;
    float pcx = cx + dd.x * w, pcy = cy + dd.y * h;
    float pw = w * expf(fminf(dd.z, MAXD));
    float ph = h * expf(fminf(dd.w, MAXD));
    float bx = pcx - 0.5f * pw, by = pcy - 0.5f * ph;
    float bz = pcx + 0.5f * pw, bw = pcy + 0.5f * ph;

    const float4* cp = (const float4*)(p.cls[l]) + (size_t)idx * 4;
    float sg[16];
    #pragma unroll
    for (int g = 0; g < 4; g++) {
        float4 v = cp[g];
        sg[4 * g + 0] = 1.0f / (1.0f + expf(-v.x));
        sg[4 * g + 1] = 1.0f / (1.0f + expf(-v.y));
        sg[4 * g + 2] = 1.0f / (1.0f + expf(-v.z));
        sg[4 * g + 3] = 1.0f / (1.0f + expf(-v.w));
    }
    // 16 rows of [bx,by,bz,bw,score,tag] == 24 float4s, 384B contiguous
    float4* q = (float4*)(out + (size_t)(l * TOPKK + rank) * (NCLS * 6));
    #pragma unroll
    for (int g = 0; g < 8; g++) {
        float ta = (float)(2 * g + 1), tb = (float)(2 * g + 2);
        q[3 * g + 0] = make_float4(bx, by, bz, bw);
        q[3 * g + 1] = make_float4(sg[2 * g], ta, bx, by);
        q[3 * g + 2] = make_float4(bz, bw, sg[2 * g + 1], tb);
    }
}

extern "C" void kernel_launch(void* const* d_in, const int* in_sizes, int n_in,
                              void* d_out, int out_size, void* d_ws, size_t ws_size,
                              hipStream_t stream) {
    (void)in_sizes; (void)n_in; (void)out_size; (void)d_ws; (void)ws_size;
    Ptrs p;
    for (int l = 0; l < NLEV; l++) {
        p.anc[l] = (const float*)d_in[3 * l + 0];
        p.cls[l] = (const float*)d_in[3 * l + 1];
        p.reg[l] = (const float*)d_in[3 * l + 2];
    }

    // Prefer the verified 1023-block shape (4/CU) if the runtime occupancy
    // calculator guarantees residency; else the r7-verified 512.
    static int s_which = -1;
    if (s_which < 0) {
        int bpcu = 0;
        if (hipOccupancyMaxActiveBlocksPerMultiprocessor(
                &bpcu, (const void*)k_fused<3u, 1023u>, 256, 0) != hipSuccess)
            bpcu = 0;
        int dev = 0, ncu = 0;
        (void)hipGetDevice(&dev);
        if (hipDeviceGetAttribute(&ncu, hipDeviceAttributeMultiprocessorCount,
                                  dev) != hipSuccess || ncu < 1)
            ncu = 0;
        s_which = (bpcu >= 4 && (long long)bpcu * ncu >= 1023) ? 1 : 0;
    }

    float* out = (float*)d_out;
    // Single dispatch: no memset. Barrier state is epoch-tagged, hist/cnt
    // are bank-alternated and zeroed by the PREVIOUS launch (first launch
    // uses the module-load .bss zeros).
    if (s_which == 1) {
        k_fused<3u, 1023u><<<dim3(1023), dim3(256), 0, stream>>>(p, out);
    } else {
        k_fused<6u, 512u><<<dim3(512), dim3(256), 0, stream>>>(p, out);
    }
}

// Round 13
// 164.188 us; speedup vs baseline: 1.0243x; 1.0243x over previous
//
#include <hip/hip_runtime.h>
#include <math.h>

#define NLEV 5
#define TOPKK 1000
#define NCLS 16
#define NPART 16                 // cand partitions (by chunk id)
#define HP 16u                   // histogram partial copies
#define PART_CAP 256
#define CAND_TOT 2048
#define NCHUNK 3069u             // 785664 / 256
#define HISTSZ (NLEV * 256)      // 1280 u32 per copy
#define HIST_U32 (HP * HISTSZ)   // 20480 u32 per hist per bank
#define CNT_U32 (NLEV * NPART * 16)          // 1280 u32 (padded counters)
#define GO_OFF 2048u             // go-words start (u32 idx) within a bar set
#define BAR_U32 8192u            // per instance: flags[0..NB-1], go @GO_OFF+b*4
#define CLEAN_U32 (2u * HIST_U32 + CNT_U32)  // next-bank words to zero

// ---- persistent device state (module .bss: zero at load, NOT poisoned) ---
// Epoch-tagged barriers + bank-alternating hist/cnt: no per-launch memset.
// Launch e tags barrier words with e+1 (stale tags never alias), uses
// hist/cnt bank e&1, zeroes bank (e+1)&1 for the next launch. g_epoch is
// device state -> correct under graph-capture and rocprof replays.
__device__ unsigned g_epoch;
__device__ unsigned g_bar[3u * BAR_U32];
__device__ unsigned g_hist[2][2][HIST_U32];    // [bank][A=0/B=1][...]
__device__ unsigned g_cnt[2][CNT_U32];
__device__ unsigned long long g_cand[NLEV * NPART * PART_CAP];

// LLC-coherent accessors: agent-scope relaxed atomics bypass per-XCD L2 and
// serialize at the LLC. All cross-block data uses these; no release/acquire
// fences anywhere (gfx950 fences lower to buffer_wbl2/buffer_inv = full-L2
// writeback/invalidate -- ~7us/barrier, removed in r7).
__device__ __forceinline__ unsigned g_load(const unsigned* p) {
    return __hip_atomic_load(p, __ATOMIC_RELAXED, __HIP_MEMORY_SCOPE_AGENT);
}
__device__ __forceinline__ unsigned long long g_load64(const unsigned long long* p) {
    return __hip_atomic_load(p, __ATOMIC_RELAXED, __HIP_MEMORY_SCOPE_AGENT);
}
__device__ __forceinline__ void g_store(unsigned* p, unsigned v) {
    __hip_atomic_store(p, v, __ATOMIC_RELAXED, __HIP_MEMORY_SCOPE_AGENT);
}
__device__ __forceinline__ void g_store64(unsigned long long* p, unsigned long long v) {
    __hip_atomic_store(p, v, __ATOMIC_RELAXED, __HIP_MEMORY_SCOPE_AGENT);
}

// chunk-index level boundaries: 2304, 2880, 3024, 3060 — divisible by 2, 3
// and 6, so blocks are level-pure for CPB in {2,3,6}.
__device__ __forceinline__ int lev_of_chunk(unsigned c) {
    if (c < 2304u) return 0;
    if (c < 2880u) return 1;
    if (c < 3024u) return 2;
    if (c < 3060u) return 3;
    return 4;
}
__device__ __forceinline__ unsigned lev_base(int l) {   // entry base per level
    unsigned b = 0u;
    if (l == 1) b = 589824u;
    if (l == 2) b = 737280u;
    if (l == 3) b = 774144u;
    if (l == 4) b = 783360u;
    return b;
}

struct Ptrs {
    const float* anc[NLEV];
    const float* cls[NLEV];
    const float* reg[NLEV];
};

// order-preserving float32 -> uint32 (larger uint == larger float)
__device__ __forceinline__ unsigned f2key(float f) {
    unsigned u = __float_as_uint(f);
    return (u & 0x80000000u) ? ~u : (u | 0x80000000u);
}

__device__ __forceinline__ float max4(float4 v) {
    return fmaxf(fmaxf(v.x, v.y), fmaxf(v.z, v.w));
}

// ---- fence-free store-based grid barrier (r7-r12 design, epoch-tagged) ---
//   flags[b]   = inst[b]              one word per block, tagged with e+1
//   go[b]      = inst[GO_OFF + b*4]   PRIVATE go word per block (16B stride)
// ORDERING: __syncthreads() before arrival drains vmcnt(0) in every wave, so
// all the block's LLC-bound atomics complete before the flag store; all
// cross-block data moves via agent-scope atomics (LLC = serialization
// point) => flag-observed implies data-visible. No wbl2/inv anywhere.
__device__ __forceinline__ void bar_arrive(unsigned* inst, unsigned tag) {
    if (threadIdx.x == 0) g_store(inst + blockIdx.x, tag);
}

// block 0 only, ALL threads participate. Sweep = W INDEPENDENT loads (all
// issued before any use -> one vmcnt wait, the r9/r10 lesson).
template<unsigned NBV>
__device__ __forceinline__ void bar_monitor_fanout(unsigned* inst, unsigned* wsh,
                                                   unsigned tag) {
    constexpr unsigned W = (NBV + 255u) / 256u;
    const unsigned t = (unsigned)threadIdx.x;
    for (;;) {
        unsigned f[W];
        #pragma unroll
        for (unsigned i = 0; i < W; i++) {
            unsigned idx = i * 256u + t;
            f[i] = (idx < NBV) ? g_load(inst + idx) : tag;
        }
        bool all = true;
        #pragma unroll
        for (unsigned i = 0; i < W; i++) all = all && (f[i] == tag);
        unsigned long long bal = __ballot(all);
        if ((t & 63u) == 0) wsh[t >> 6] = (bal == 0xFFFFFFFFFFFFFFFFull) ? 1u : 0u;
        __syncthreads();
        bool done = wsh[0] && wsh[1] && wsh[2] && wsh[3];
        __syncthreads();
        if (done) break;
        __builtin_amdgcn_s_sleep(1);
    }
    for (unsigned idx = t; idx < NBV; idx += 256u)        // private go words
        g_store(inst + GO_OFF + idx * 4u, tag);
}

__device__ __forceinline__ void bar_waitgo(unsigned* inst, unsigned tag) {
    while (g_load(inst + GO_OFF + blockIdx.x * 4u) != tag)
        __builtin_amdgcn_s_sleep(2);
}

template<unsigned NBV>
__device__ __forceinline__ void gridbar(unsigned* inst, unsigned* wsh, unsigned tag) {
    __syncthreads();                       // drains vmcnt in all waves
    bar_arrive(inst, tag);
    if (blockIdx.x == 0) {
        bar_monitor_fanout<NBV>(inst, wsh, tag);
    } else if (threadIdx.x == 0) {
        bar_waitgo(inst, tag);
    }
    __syncthreads();
}

// suffix-select over 256 bins (bin == threadIdx) via wave shuffles.
// Finds bin holding the rem-th largest; aux[0]=bin, aux[1]=remainder.
// (verbatim r5-r12 core, absmax-0 verified)
__device__ __forceinline__ void sel256(unsigned c, unsigned rem,
                                       unsigned* wsum, unsigned* aux) {
    int t = threadIdx.x, lane = t & 63, wv = t >> 6;
    unsigned s = c;                          // suffix-sum over lanes >= mine
    #pragma unroll
    for (int d = 1; d < 64; d <<= 1) {
        unsigned o = __shfl_down(s, d, 64);
        if (lane + d < 64) s += o;
    }
    if (lane == 0) wsum[wv] = s;             // wave total
    __syncthreads();
    unsigned incl = s;                       // + totals of higher-bin waves
    #pragma unroll
    for (int w2 = 1; w2 < 4; w2++) if (wv + w2 < 4) incl += wsum[wv + w2];
    unsigned above = incl - c;
    if (above < rem && rem <= incl) {        // exactly one winner thread
        aux[0] = (unsigned)t;
        aux[1] = rem - above;
    }
    __syncthreads();
}

// ILP copy-sum: issue all HP hist-copy loads before summing (one vmcnt wait
// instead of a 16-deep serialized LLC chain -- the r9 lesson).
__device__ __forceinline__ unsigned hist_sum(const unsigned* hist, int lev) {
    unsigned vv[HP];
    #pragma unroll
    for (unsigned pp = 0; pp < HP; pp++)
        vv[pp] = g_load(hist + pp * HISTSZ + (unsigned)lev * 256u
                        + (unsigned)threadIdx.x);
    unsigned s = 0;
    #pragma unroll
    for (unsigned pp = 0; pp < HP; pp++) s += vv[pp];
    return s;
}

// One persistent kernel, ONE dispatch. r13: MLP via TLP — r12 showed the
// register allocator refuses source-level load hoisting (VGPR stayed 36),
// so per-wave ILP is capped ~5 loads; instead run 6 blocks/CU (NB=1535,
// CPB=2 -> 24 waves/CU, ~7.5KB in flight vs the ~9KB the HBM latency-BW
// product needs). Wave count is the only occupancy limiter (VGPR 36,
// LDS 17.9KB). Selection semantics bit-identical to verified r0.
template<unsigned CPBV, unsigned NBV>
__global__ __launch_bounds__(256, 2) void k_fused(Ptrs p, float* out) {
    __shared__ unsigned long long lbuf[CAND_TOT];   // 16 KB (rank phase only)
    __shared__ unsigned hh[256];
    __shared__ unsigned wsum[4];
    __shared__ unsigned wsh[4];
    __shared__ unsigned aux[33];

    constexpr bool EXACT = (CPBV * NBV == NCHUNK);  // no tail guard needed
    const unsigned b = blockIdx.x;
    const int t = threadIdx.x;
    const unsigned c0 = b * CPBV;
    const int lev = lev_of_chunk(c0);
    const unsigned ebase = lev_base(lev);

    const unsigned e   = g_load(&g_epoch);   // stable: prev launch fully done
    const unsigned tag = e + 1u;             // never aliases stale (.bss=0)
    const unsigned bk  = e & 1u;
    unsigned* histA = g_hist[bk][0];
    unsigned* histB = g_hist[bk][1];
    unsigned* cnt   = g_cnt[bk];
    unsigned* bar0 = g_bar;
    unsigned* bar1 = g_bar + BAR_U32;
    unsigned* bar2 = g_bar + 2u * BAR_U32;

    // ---- Phase A1: coalesced loads + 4-lane shuffle max-reduce ----
    // Thread t loads float4 #(g*256+t) of each chunk (16B lane stride,
    // fully coalesced); 2-step shfl_xor max in each 4-lane group; thread t
    // keeps entry eloc = (t&3)*64 + (t>>2) (bijection; hist is permutation-
    // invariant, compact stores loc explicitly -> output bit-identical).
    unsigned keys[CPBV];
    const float4* f4p = (const float4*)(p.cls[lev]);
    #pragma unroll
    for (unsigned j = 0; j < CPBV; j++) {
        unsigned ch = c0 + j;
        unsigned k = 0u;
        if (EXACT || ch < NCHUNK) {
            unsigned base4 = (ch * 256u - ebase) * 4u;
            float4 a0 = f4p[base4 + 0u * 256u + (unsigned)t];
            float4 a1 = f4p[base4 + 1u * 256u + (unsigned)t];
            float4 a2 = f4p[base4 + 2u * 256u + (unsigned)t];
            float4 a3 = f4p[base4 + 3u * 256u + (unsigned)t];
            float m0 = max4(a0), m1 = max4(a1), m2 = max4(a2), m3 = max4(a3);
            m0 = fmaxf(m0, __shfl_xor(m0, 1, 64));
            m0 = fmaxf(m0, __shfl_xor(m0, 2, 64));
            m1 = fmaxf(m1, __shfl_xor(m1, 1, 64));
            m1 = fmaxf(m1, __shfl_xor(m1, 2, 64));
            m2 = fmaxf(m2, __shfl_xor(m2, 1, 64));
            m2 = fmaxf(m2, __shfl_xor(m2, 2, 64));
            m3 = fmaxf(m3, __shfl_xor(m3, 1, 64));
            m3 = fmaxf(m3, __shfl_xor(m3, 2, 64));
            int g = t & 3;
            float mm = (g == 0) ? m0 : (g == 1) ? m1 : (g == 2) ? m2 : m3;
            k = f2key(mm);
        }
        keys[j] = k;
    }
    // ---- Phase A2: block byte-1 hist; one flush into 1-of-16 copies ----
    hh[t] = 0u;
    __syncthreads();
    #pragma unroll
    for (unsigned j = 0; j < CPBV; j++)
        if (EXACT || c0 + j < NCHUNK) atomicAdd(&hh[keys[j] >> 24], 1u);
    __syncthreads();
    {
        unsigned v = hh[t];
        if (v) atomicAdd(&histA[(b & (HP - 1u)) * HISTSZ
                                + (unsigned)lev * 256u + (unsigned)t], v);
    }
    gridbar<NBV>(bar0, wsh, tag);

    // ---- Select byte-1 for OWN level only (ILP copy-sum) ----
    sel256(hist_sum(histA, lev), TOPKK, wsum, aux);
    unsigned binA = aux[0], remA = aux[1];
    __syncthreads();

    // ---- Phase C: byte-2 hist of keys matching byte-1 prefix ----
    hh[t] = 0u;
    __syncthreads();
    #pragma unroll
    for (unsigned j = 0; j < CPBV; j++) {
        unsigned k = keys[j];
        if ((EXACT || (c0 + j) < NCHUNK) && (k >> 24) == binA)
            atomicAdd(&hh[(k >> 16) & 0xFFu], 1u);
    }
    __syncthreads();
    {
        unsigned v = hh[t];
        if (v) atomicAdd(&histB[(b & (HP - 1u)) * HISTSZ
                                + (unsigned)lev * 256u + (unsigned)t], v);
    }
    gridbar<NBV>(bar1, wsh, tag);

    // ---- Select byte-2 -> 16-bit threshold (identical semantics) ----
    sel256(hist_sum(histB, lev), remA, wsum, aux);
    unsigned thresh = (binA << 24) | (aux[0] << 16);
    __syncthreads();

    // ---- Phase E: compact candidates (loc uses the phase-A permutation) ----
    const unsigned eloc = (((unsigned)t & 3u) << 6) | ((unsigned)t >> 2);
    #pragma unroll
    for (unsigned j = 0; j < CPBV; j++) {
        unsigned ch = c0 + j;
        unsigned k = keys[j];
        if ((EXACT || ch < NCHUNK) && k >= thresh) {
            unsigned loc = ch * 256u - ebase + eloc;
            unsigned part = ch & (NPART - 1u);
            unsigned slot = atomicAdd(&cnt[(lev * NPART + part) * 16u], 1u);
            if (slot < PART_CAP)
                g_store64(&g_cand[((size_t)(lev * NPART + part)) * PART_CAP + slot],
                          ((unsigned long long)k << 32) | (unsigned)(~loc));
        }
    }

    // ---- Exit-flag: arrive FIRST; cleanup AFTER arrival (off the barrier
    //      critical path; bank bk^1 is disjoint from everything F reads) ----
    bool ranker = b < (unsigned)(NLEV * 8);
    __syncthreads();                       // drains vmcnt (cand stores acked)
    bar_arrive(bar2, tag);
    {
        unsigned bk1 = bk ^ 1u;
        for (unsigned i = b * 256u + (unsigned)t; i < CLEAN_U32; i += NBV * 256u) {
            if (i < 2u * HIST_U32) g_store(&g_hist[bk1][0][0] + i, 0u);
            else                   g_store(&g_cnt[bk1][i - 2u * HIST_U32], 0u);
        }
    }
    if (b == 0) {
        bar_monitor_fanout<NBV>(bar2, wsh, tag);
        if (t == 0) g_store(&g_epoch, tag);   // all blocks arrived: safe
    } else if (ranker) {
        if (t == 0) bar_waitgo(bar2, tag);
    } else {
        return;                               // cleanup stores retire at kernel end
    }
    __syncthreads();

    // ---- Phase F: rank-by-counting + emit (verified round-0 logic) ----
    const float MAXD = 4.135166556742356f;   // log(1000/16)
    int l = (int)(b >> 3);
    unsigned sl = b & 7u;

    if (t < NPART) {
        unsigned cc = g_load(cnt + (l * NPART + t) * 16u);
        aux[t] = (cc > PART_CAP) ? PART_CAP : cc;
    }
    __syncthreads();
    if (t == 0) {
        unsigned o = 0;
        for (int pp = 0; pp < NPART; pp++) { aux[16 + pp] = o; o += aux[pp]; }
        aux[32] = (o > CAND_TOT) ? CAND_TOT : o;
    }
    __syncthreads();
    unsigned n = aux[32];
    {
        // each thread handles entry #t of each part: 16 guarded INDEPENDENT
        // loads, then 16 LDS stores (ILP-batched).
        unsigned long long tv[NPART];
        unsigned vok = 0u;
        #pragma unroll
        for (int pp = 0; pp < NPART; pp++) {
            bool ok = (unsigned)t < aux[pp];
            if (ok) tv[pp] = g_load64(&g_cand[((size_t)(l * NPART + pp)) * PART_CAP
                                              + (unsigned)t]);
            vok |= ok ? (1u << pp) : 0u;
        }
        #pragma unroll
        for (int pp = 0; pp < NPART; pp++) {
            if (vok & (1u << pp)) {
                unsigned dst = aux[16 + pp] + (unsigned)t;
                if (dst < CAND_TOT) lbuf[dst] = tv[pp];
            }
        }
    }
    __syncthreads();

    unsigned j = sl * 256u + (unsigned)t;
    if (j >= n) return;
    unsigned long long my = lbuf[j];
    unsigned rank = 0;
    #pragma unroll 8
    for (unsigned q = 0; q < n; q++) rank += (lbuf[q] > my) ? 1u : 0u;
    if (rank >= TOPKK) return;

    unsigned idx = ~((unsigned)(my & 0xFFFFFFFFull));
    float4 an = ((const float4*)p.anc[l])[idx];
    float4 dd = ((const float4*)p.reg[l])[(size_t)idx * 2];
    float w = an.z - an.x, h = an.w - an.y;
    float cx = an.x + 0.5f * w, cy = an.y + 0.5f * h;
    float pcx = cx + dd.x * w, pcy = cy + dd.y * h;
    float pw = w * expf(fminf(dd.z, MAXD));
    float ph = h * expf(fminf(dd.w, MAXD));
    float bx = pcx - 0.5f * pw, by = pcy - 0.5f * ph;
    float bz = pcx + 0.5f * pw, bw = pcy + 0.5f * ph;

    const float4* cp = (const float4*)(p.cls[l]) + (size_t)idx * 4;
    float sg[16];
    #pragma unroll
    for (int g = 0; g < 4; g++) {
        float4 v = cp[g];
        sg[4 * g + 0] = 1.0f / (1.0f + expf(-v.x));
        sg[4 * g + 1] = 1.0f / (1.0f + expf(-v.y));
        sg[4 * g + 2] = 1.0f / (1.0f + expf(-v.z));
        sg[4 * g + 3] = 1.0f / (1.0f + expf(-v.w));
    }
    // 16 rows of [bx,by,bz,bw,score,tag] == 24 float4s, 384B contiguous
    float4* q = (float4*)(out + (size_t)(l * TOPKK + rank) * (NCLS * 6));
    #pragma unroll
    for (int g = 0; g < 8; g++) {
        float ta = (float)(2 * g + 1), tb = (float)(2 * g + 2);
        q[3 * g + 0] = make_float4(bx, by, bz, bw);
        q[3 * g + 1] = make_float4(sg[2 * g], ta, bx, by);
        q[3 * g + 2] = make_float4(bz, bw, sg[2 * g + 1], tb);
    }
}

extern "C" void kernel_launch(void* const* d_in, const int* in_sizes, int n_in,
                              void* d_out, int out_size, void* d_ws, size_t ws_size,
                              hipStream_t stream) {
    (void)in_sizes; (void)n_in; (void)out_size; (void)d_ws; (void)ws_size;
    Ptrs p;
    for (int l = 0; l < NLEV; l++) {
        p.anc[l] = (const float*)d_in[3 * l + 0];
        p.cls[l] = (const float*)d_in[3 * l + 1];
        p.reg[l] = (const float*)d_in[3 * l + 2];
    }

    // Shape gated by the runtime occupancy calculator (cached host-only
    // queries -> graph-capture safe). Prefer 1535 blocks (6/CU, max TLP for
    // the scan), else the r8/r12-verified 1023, else the r7-verified 512.
    static int s_which = -1;
    if (s_which < 0) {
        int bpcu = 0;
        if (hipOccupancyMaxActiveBlocksPerMultiprocessor(
                &bpcu, (const void*)k_fused<2u, 1535u>, 256, 0) != hipSuccess)
            bpcu = 0;
        int dev = 0, ncu = 0;
        (void)hipGetDevice(&dev);
        if (hipDeviceGetAttribute(&ncu, hipDeviceAttributeMultiprocessorCount,
                                  dev) != hipSuccess || ncu < 1)
            ncu = 0;
        long long cap = (long long)bpcu * (long long)ncu;
        s_which = (bpcu >= 6 && cap >= 1535) ? 2
                : (bpcu >= 4 && cap >= 1023) ? 1 : 0;
    }

    float* out = (float*)d_out;
    // Single dispatch: no memset. Barrier state is epoch-tagged, hist/cnt
    // are bank-alternated and zeroed by the PREVIOUS launch (first launch
    // uses the module-load .bss zeros).
    if (s_which == 2) {
        k_fused<2u, 1535u><<<dim3(1535), dim3(256), 0, stream>>>(p, out);
    } else if (s_which == 1) {
        k_fused<3u, 1023u><<<dim3(1023), dim3(256), 0, stream>>>(p, out);
    } else {
        k_fused<6u, 512u><<<dim3(512), dim3(256), 0, stream>>>(p, out);
    }
}